// Round 21
// baseline (94.108 us; speedup 1.0000x reference)
//
#include <hip/hip_runtime.h>

typedef __attribute__((ext_vector_type(8))) short bf16x8;
typedef __attribute__((ext_vector_type(4))) float f32x4;
typedef __attribute__((ext_vector_type(16))) float f32x16;
typedef __attribute__((ext_vector_type(2))) unsigned int u32x2;

#define DEVI static __device__ __forceinline__

namespace {
constexpr int NSEQ = 2048, NH = 16;
constexpr int D = 1024, D3 = 3072;
}

DEVI unsigned short f2bf(float f) {
  union { float f; unsigned int u; } v; v.f = f;
  unsigned int r = v.u + 0x7FFFu + ((v.u >> 16) & 1u);
  return (unsigned short)(r >> 16);
}

DEVI void gload16(const unsigned short* g, unsigned short* lds_) {
  __builtin_amdgcn_global_load_lds(
      (const __attribute__((address_space(1))) unsigned int*)g,
      (__attribute__((address_space(3))) unsigned int*)lds_, 16, 0, 0);
}

DEVI f32x4 mfma16(bf16x8 a, bf16x8 b, f32x4 c) {
  return __builtin_amdgcn_mfma_f32_16x16x32_bf16(a, b, c, 0, 0, 0);
}

DEVI f32x16 mfma32(bf16x8 a, bf16x8 b, f32x16 c) {
  return __builtin_amdgcn_mfma_f32_32x32x16_bf16(a, b, c, 0, 0, 0);
}

DEVI float exp2g(float x) {
#if __has_builtin(__builtin_amdgcn_exp2f)
  return __builtin_amdgcn_exp2f(x);
#else
  return exp2f(x);
#endif
}

DEVI unsigned int cvtpk(float a, float b) {
  unsigned int r;
  asm("v_cvt_pk_bf16_f32 %0, %1, %2" : "=v"(r) : "v"(a), "v"(b));
  return r;
}

DEVI u32x2 pswap2(unsigned int a, unsigned int b) {
  return __builtin_amdgcn_permlane32_swap(a, b, false, false);
}
DEVI float xmax_halves(float v) {
  union { float f; unsigned int u; } c; c.f = v;
  u32x2 r = pswap2(c.u, c.u);
  union { unsigned int u; float f; } x, y; x.u = r.x; y.u = r.y;
  return fmaxf(x.f, y.f);
}

union U4 { unsigned int u[4]; bf16x8 v; };

// ---------------- prep: cast x -> bf16  +  transpose/cast W -> Wt ----------
__global__ __launch_bounds__(256) void prep_k(const float* __restrict__ x,
                                              const float* __restrict__ W,
                                              unsigned short* __restrict__ xb,
                                              unsigned short* __restrict__ Wt) {
  __shared__ float t[32][33];
  const int bid = blockIdx.x;
  if (bid < 4096) {
    int i = (bid * 256 + threadIdx.x) * 4;
    float4 v = *reinterpret_cast<const float4*>(x + i);
    ushort4 o;
    o.x = f2bf(v.x); o.y = f2bf(v.y); o.z = f2bf(v.z); o.w = f2bf(v.w);
    *reinterpret_cast<ushort4*>(xb + i) = o;
  } else {
    const int b2 = bid - 4096;
    const int c0 = (b2 % 96) * 32, k0 = (b2 / 96) * 32;
    const int tx = threadIdx.x & 31, ty = threadIdx.x >> 5;  // ty 0..7
#pragma unroll
    for (int r = 0; r < 32; r += 8)
      t[ty + r][tx] = W[(size_t)(k0 + ty + r) * D3 + c0 + tx];
    __syncthreads();
#pragma unroll
    for (int r = 0; r < 32; r += 8)
      Wt[(size_t)(c0 + ty + r) * D + k0 + tx] = f2bf(t[tx][ty + r]);
  }
}

// ---------------- QKV GEMM: [4096x1024] x [1024x3072] -------------
// 128x128 tile, BK=64 (16 K-steps -> HALF the vmcnt(0)+barrier drains of
// BK=32), 2x2 waves of 64x64, 16x16x32 bf16 MFMA. Fragments read per-ks
// half (af[4]/bfr[4] reused) to hold VGPR ~112 -> occupancy unchanged.
// Chunk-XOR swizzle (c ^ (row&7), 8 chunks/row) both-sides as in attn.
__global__ __launch_bounds__(256) void qkv_gemm_k(const unsigned short* __restrict__ xb,
                                                  const unsigned short* __restrict__ Wt,
                                                  unsigned short* __restrict__ qw,
                                                  unsigned short* __restrict__ kw,
                                                  unsigned short* __restrict__ vtw) {
  __shared__ unsigned short smA[128 * 64];
  __shared__ unsigned short smB[128 * 64];
  const int tid = threadIdx.x, w = tid >> 6, l = tid & 63;
  const int m0 = blockIdx.x * 128, n0 = blockIdx.y * 128;
  const int wm = w >> 1, wn = w & 1;

  const unsigned short* ga[4]; const unsigned short* gb[4];
  unsigned short* la[4]; unsigned short* lb[4];
#pragma unroll
  for (int i = 0; i < 4; ++i) {
    int idx = tid + i * 256;
    int row = idx >> 3;                       // 0..127
    int blk = (idx & 7) ^ (row & 7);          // pre-swizzled global source
    ga[i] = xb + (size_t)(m0 + row) * D + blk * 8;
    gb[i] = Wt + (size_t)(n0 + row) * D + blk * 8;
    la[i] = smA + (w * 64 + i * 256) * 8;     // wave-uniform linear LDS dest
    lb[i] = smB + (w * 64 + i * 256) * 8;
  }

  f32x4 acc[4][4];
#pragma unroll
  for (int a = 0; a < 4; ++a)
#pragma unroll
    for (int b = 0; b < 4; ++b) acc[a][b] = (f32x4){0.f, 0.f, 0.f, 0.f};

  for (int kt = 0; kt < D / 64; ++kt) {
    __syncthreads();
#pragma unroll
    for (int i = 0; i < 4; ++i) {
      gload16(ga[i] + kt * 64, la[i]);
      gload16(gb[i] + kt * 64, lb[i]);
    }
    asm volatile("s_waitcnt vmcnt(0)" ::: "memory");
    __syncthreads();

#pragma unroll
    for (int ks = 0; ks < 2; ++ks) {
      bf16x8 af[4], bfr[4];
#pragma unroll
      for (int a = 0; a < 4; ++a) {
        int arow = wm * 64 + a * 16 + (l & 15);
        int blk = (ks * 4 + (l >> 4)) ^ (arow & 7);
        af[a] = *reinterpret_cast<const bf16x8*>(smA + arow * 64 + blk * 8);
      }
#pragma unroll
      for (int b = 0; b < 4; ++b) {
        int brow = wn * 64 + b * 16 + (l & 15);
        int blk = (ks * 4 + (l >> 4)) ^ (brow & 7);
        bfr[b] = *reinterpret_cast<const bf16x8*>(smB + brow * 64 + blk * 8);
      }
#pragma unroll
      for (int a = 0; a < 4; ++a)
#pragma unroll
        for (int b = 0; b < 4; ++b)
          acc[a][b] = mfma16(af[a], bfr[b], acc[a][b]);
    }
  }

  const int which = n0 >> 10;
#pragma unroll
  for (int a = 0; a < 4; ++a) {
#pragma unroll
    for (int b = 0; b < 4; ++b) {
#pragma unroll
      for (int r = 0; r < 4; ++r) {
        int grow = m0 + wm * 64 + a * 16 + (l >> 4) * 4 + r;
        int gcol = n0 + wn * 64 + b * 16 + (l & 15);
        float v = acc[a][b][r];
        int bb = grow >> 11, n = grow & 2047;
        int cc = gcol & 1023, h = cc >> 6, dh = cc & 63;
        size_t bh = (size_t)bb * NH + h;
        if (which == 0)
          qw[(bh * NSEQ + n) * 64 + dh] = f2bf(v * 0.18033688011112042f);
        else if (which == 1)
          kw[(bh * NSEQ + n) * 64 + dh] = f2bf(v);
        else
          vtw[(bh * 64 + dh) * NSEQ + n] = f2bf(v);
      }
    }
  }
}

// ---------------- causal flash attention: 32x32 MFMA, in-register P -------
// R10 structure; K-fragment loads hoisted ahead of the QK MFMA cluster
// (8 reads in flight -> one LDS latency) and V-fragment loads issued right
// after QK so their latency hides under softmax/pack (T14-lite).
__global__ __launch_bounds__(256, 2) void attn_k(const unsigned short* __restrict__ qw,
                                                 const unsigned short* __restrict__ kw,
                                                 const unsigned short* __restrict__ vtw,
                                                 float* __restrict__ out) {
  __shared__ __align__(16) char lds[66560];  // 2 slots x 32KB (KV pairs) + 1KB m/l
  const int tid = threadIdx.x, w = tid >> 6, l = tid & 63;
  const int hi = l >> 5, ql = l & 31;
  const int qsub = w >> 1, par = w & 1;

  const int wg = blockIdx.x;               // 512 blocks
  const int xcd = wg & 7, rest = wg >> 3;
  const int bhl = rest >> 4;               // local bh on this XCD
  const int j = rest & 15;                 // pair index
  const int bh = xcd * 4 + bhl;
  const int bb = bh >> 4, h = bh & 15;

  const unsigned short* qb = qw + (size_t)bh * NSEQ * 64;
  const unsigned short* kb = kw + (size_t)bh * NSEQ * 64;
  const unsigned short* vb = vtw + (size_t)bh * 64 * NSEQ;

  const int r0 = tid >> 3, c0 = (tid & 7) ^ (r0 & 7);
  const int r1 = (tid + 256) >> 3, c1 = ((tid + 256) & 7) ^ (r1 & 7);
  const int wbase = w * 512;               // ushorts: w*64 lanes * 8

#define STAGE(SL, PR)                                                            \
  do {                                                                           \
    const int t0_ = 2 * (PR), t1_ = 2 * (PR) + 1;                                \
    unsigned short* k0d = (unsigned short*)(lds + (SL) * 32768) + wbase;         \
    unsigned short* v0d = (unsigned short*)(lds + (SL) * 32768 + 8192) + wbase;  \
    unsigned short* k1d = (unsigned short*)(lds + (SL) * 32768 + 16384) + wbase; \
    unsigned short* v1d = (unsigned short*)(lds + (SL) * 32768 + 24576) + wbase; \
    gload16(kb + (((size_t)t0_ * 64 + r0) * 64 + c0 * 8), k0d);                  \
    gload16(kb + (((size_t)t0_ * 64 + r1) * 64 + c1 * 8), k0d + 2048);           \
    gload16(vb + ((size_t)r0 * NSEQ + t0_ * 64 + c0 * 8), v0d);                  \
    gload16(vb + ((size_t)r1 * NSEQ + t0_ * 64 + c1 * 8), v0d + 2048);           \
    gload16(kb + (((size_t)t1_ * 64 + r0) * 64 + c0 * 8), k1d);                  \
    gload16(kb + (((size_t)t1_ * 64 + r1) * 64 + c1 * 8), k1d + 2048);           \
    gload16(vb + ((size_t)r0 * NSEQ + t1_ * 64 + c0 * 8), v1d);                  \
    gload16(vb + ((size_t)r1 * NSEQ + t1_ * 64 + c1 * 8), v1d + 2048);           \
  } while (0)

  for (int seg = 0; seg < 2; ++seg) {
    const int qt = seg ? j : (31 - j);     // heavy q-tile first
    const int qbase = qt * 64;
    const int qg = qbase + qsub * 32 + ql; // this lane's q-row (global)

    bf16x8 qf[4];
#pragma unroll
    for (int ds = 0; ds < 4; ++ds)
      qf[ds] = *reinterpret_cast<const bf16x8*>(qb + (size_t)qg * 64 + ds * 16 + hi * 8);

    float m = -1e30f, lsum = 0.f;
    f32x16 O0, O1;
#pragma unroll
    for (int r2 = 0; r2 < 16; ++r2) { O0[r2] = 0.f; O1[r2] = 0.f; }

    const int nsup = (qt >> 1) + 1;
    STAGE(0, 0);
    for (int s = 0; s < nsup; ++s) {
      __syncthreads();                     // drains + publishes slot s&1
      if (s + 1 < nsup) STAGE((s + 1) & 1, s + 1);
      const int t = 2 * s + par;
      if (t <= qt) {
        const char* Kb = lds + (s & 1) * 32768 + par * 16384;
        const char* Vb = Kb + 8192;

        // hoisted K-fragment loads: 8 ds_read_b128 in flight before MFMAs
        bf16x8 kf[8];
#pragma unroll
        for (int ds = 0; ds < 4; ++ds) {
          kf[ds] = *reinterpret_cast<const bf16x8*>(
              Kb + ql * 128 + (((2 * ds + hi) ^ (ql & 7)) << 4));
          kf[4 + ds] = *reinterpret_cast<const bf16x8*>(
              Kb + (32 + ql) * 128 + (((2 * ds + hi) ^ (ql & 7)) << 4));
        }

        // QK: S^T[64k][32q], C rows=k, col q=ql
        f32x16 S0, S1;
#pragma unroll
        for (int r2 = 0; r2 < 16; ++r2) { S0[r2] = 0.f; S1[r2] = 0.f; }
        __builtin_amdgcn_s_setprio(1);
#pragma unroll
        for (int ds = 0; ds < 4; ++ds) {
          S0 = mfma32(kf[ds], qf[ds], S0);
          S1 = mfma32(kf[4 + ds], qf[ds], S1);
        }
        __builtin_amdgcn_s_setprio(0);

        // issue V-fragment loads NOW; latency hides under softmax/pack
        bf16x8 vf[8];
#pragma unroll
        for (int ks = 0; ks < 4; ++ks) {
          vf[ks] = *reinterpret_cast<const bf16x8*>(
              Vb + ql * 128 + (((2 * ks + hi) ^ (ql & 7)) << 4));
          vf[4 + ks] = *reinterpret_cast<const bf16x8*>(
              Vb + (32 + ql) * 128 + (((2 * ks + hi) ^ (ql & 7)) << 4));
        }

        if (t == qt) {  // causal mask on diagonal tile
#pragma unroll
          for (int reg = 0; reg < 16; ++reg) {
            const int krow = (reg & 3) + 8 * (reg >> 2) + 4 * hi;
            if (64 * t + krow > qg) S0[reg] = -1e30f;
            if (64 * t + 32 + krow > qg) S1[reg] = -1e30f;
          }
        }

        // row max: in-lane tree + one cross-half swap
        float t0 = fmaxf(S0[0], S1[0]), t1 = fmaxf(S0[1], S1[1]);
        float t2 = fmaxf(S0[2], S1[2]), t3 = fmaxf(S0[3], S1[3]);
#pragma unroll
        for (int r2 = 4; r2 < 16; r2 += 4) {
          t0 = fmaxf(t0, fmaxf(S0[r2], S1[r2]));
          t1 = fmaxf(t1, fmaxf(S0[r2 + 1], S1[r2 + 1]));
          t2 = fmaxf(t2, fmaxf(S0[r2 + 2], S1[r2 + 2]));
          t3 = fmaxf(t3, fmaxf(S0[r2 + 3], S1[r2 + 3]));
        }
        float tmax = xmax_halves(fmaxf(fmaxf(t0, t1), fmaxf(t2, t3)));

        if (!__all(tmax <= m + 8.0f)) {   // defer-max
          const float mn = fmaxf(m, tmax);
          const float g = exp2g(m - mn);
          m = mn;
          lsum *= g;
#pragma unroll
          for (int r2 = 0; r2 < 16; ++r2) { O0[r2] *= g; O1[r2] *= g; }
        }

        // exp + row sum
        float pr0[16], pr1[16];
        float rA = 0.f, rB = 0.f, rC = 0.f, rD = 0.f;
#pragma unroll
        for (int r2 = 0; r2 < 16; r2 += 4) {
          pr0[r2] = exp2g(S0[r2] - m);     pr1[r2] = exp2g(S1[r2] - m);
          pr0[r2 + 1] = exp2g(S0[r2 + 1] - m); pr1[r2 + 1] = exp2g(S1[r2 + 1] - m);
          pr0[r2 + 2] = exp2g(S0[r2 + 2] - m); pr1[r2 + 2] = exp2g(S1[r2 + 2] - m);
          pr0[r2 + 3] = exp2g(S0[r2 + 3] - m); pr1[r2 + 3] = exp2g(S1[r2 + 3] - m);
          rA += pr0[r2] + pr1[r2];
          rB += pr0[r2 + 1] + pr1[r2 + 1];
          rC += pr0[r2 + 2] + pr1[r2 + 2];
          rD += pr0[r2 + 3] + pr1[r2 + 3];
        }
        {
          float rsum = (rA + rB) + (rC + rD);
          union { float f; unsigned int u; } c; c.f = rsum;
          u32x2 r = pswap2(c.u, c.u);
          union { unsigned int u; float f; } x, y; x.u = r.x; y.u = r.y;
          lsum += x.f + y.f;
        }

        // pack P into PV B-frags: cvt_pk + permlane32_swap
        bf16x8 pf[4];
#pragma unroll
        for (int ct = 0; ct < 2; ++ct) {
          const float* pp = ct ? pr1 : pr0;
          unsigned int u[4][2];
#pragma unroll
          for (int c = 0; c < 4; ++c) {
            u[c][0] = cvtpk(pp[4 * c], pp[4 * c + 1]);
            u[c][1] = cvtpk(pp[4 * c + 2], pp[4 * c + 3]);
          }
#pragma unroll
          for (int kk = 0; kk < 2; ++kk) {
            u32x2 rw0 = pswap2(u[2 * kk][0], u[2 * kk + 1][0]);
            u32x2 rw1 = pswap2(u[2 * kk][1], u[2 * kk + 1][1]);
            U4 f;
            f.u[0] = rw0.x; f.u[1] = rw1.x;
            f.u[2] = rw0.y; f.u[3] = rw1.y;
            pf[2 * ct + kk] = f.v;
          }
        }

        // PV: O^T[64d][32q] += V^T-frag x P-frag (vf already resident)
        __builtin_amdgcn_s_setprio(1);
#pragma unroll
        for (int ks = 0; ks < 4; ++ks) {
          O0 = mfma32(vf[ks], pf[ks], O0);
          O1 = mfma32(vf[4 + ks], pf[ks], O1);
        }
        __builtin_amdgcn_s_setprio(0);
      }
    }

    // ---- merge k-split parities (log-sum-exp) + epilogue ----
    __syncthreads();
    float* mlp = (float*)(lds + 65536);
    if (l < 32) { mlp[w * 64 + l] = m; mlp[w * 64 + 32 + l] = lsum; }
    __syncthreads();
    {
      const int pw = w ^ 1;
      const float m1 = mlp[pw * 64 + ql];
      const float l1 = mlp[pw * 64 + 32 + ql];
      const float M = fmaxf(m, m1);
      const float g0 = exp2g(m - M);
      const float g1 = exp2g(m1 - M);
      const float L = lsum * g0 + l1 * g1;
      const float phi = g0 / L;
      float* mo = (float*)lds + (qsub * 2 + par) * 2048;  // [32q][64d] swizzled
#pragma unroll
      for (int reg = 0; reg < 16; ++reg) {
        const int dr = (reg & 3) + 8 * (reg >> 2) + 4 * hi;
        const int d1 = 32 + dr;
        mo[ql * 64 + (((dr >> 2) ^ (ql & 7)) << 2) + (dr & 3)] = O0[reg] * phi;
        mo[ql * 64 + (((d1 >> 2) ^ (ql & 7)) << 2) + (d1 & 3)] = O1[reg] * phi;
      }
    }
    __syncthreads();
    {
      const int qq = tid >> 2, dq = (tid & 3) << 4;
      const float* pa = (float*)lds + ((qq >> 5) * 2 + 0) * 2048 + (qq & 31) * 64;
      const float* pb = (float*)lds + ((qq >> 5) * 2 + 1) * 2048 + (qq & 31) * 64;
      float* op = out + ((size_t)bb * NSEQ + qbase + qq) * D + h * 64 + dq;
#pragma unroll
      for (int c = 0; c < 4; ++c) {
        const int ch = ((dq >> 2) + c) ^ (qq & 7);
        float4 va = *reinterpret_cast<const float4*>(pa + ch * 4);
        float4 vb4 = *reinterpret_cast<const float4*>(pb + ch * 4);
        float4 s4 = make_float4(va.x + vb4.x, va.y + vb4.y, va.z + vb4.z, va.w + vb4.w);
        *reinterpret_cast<float4*>(op + c * 4) = s4;
      }
    }
    __syncthreads();   // protect LDS before next segment's prologue STAGE
  }
#undef STAGE
}

extern "C" void kernel_launch(void* const* d_in, const int* in_sizes, int n_in,
                              void* d_out, int out_size, void* d_ws, size_t ws_size,
                              hipStream_t stream) {
  const float* x = (const float*)d_in[0];
  const float* W = (const float*)d_in[1];
  float* out = (float*)d_out;
  char* ws = (char*)d_ws;
  unsigned short* xb  = (unsigned short*)(ws);               // 8 MB
  unsigned short* Wt  = (unsigned short*)(ws + 8388608);     // 6 MB
  unsigned short* qw  = (unsigned short*)(ws + 14680064);    // 8 MB
  unsigned short* kw  = (unsigned short*)(ws + 23068672);    // 8 MB
  unsigned short* vtw = (unsigned short*)(ws + 31457280);    // 8 MB

  prep_k<<<7168, 256, 0, stream>>>(x, W, xb, Wt);
  qkv_gemm_k<<<dim3(32, 24), 256, 0, stream>>>(xb, Wt, qw, kw, vtw);
  attn_k<<<512, 256, 0, stream>>>(qw, kw, vtw, out);
}

// Round 22
// 84.025 us; speedup vs baseline: 1.1200x; 1.1200x over previous
//
#include <hip/hip_runtime.h>

typedef __attribute__((ext_vector_type(8))) short bf16x8;
typedef __attribute__((ext_vector_type(4))) float f32x4;
typedef __attribute__((ext_vector_type(16))) float f32x16;
typedef __attribute__((ext_vector_type(2))) unsigned int u32x2;

#define DEVI static __device__ __forceinline__

namespace {
constexpr int NSEQ = 2048, NH = 16;
constexpr int D = 1024, D3 = 3072;
}

DEVI unsigned short f2bf(float f) {
  union { float f; unsigned int u; } v; v.f = f;
  unsigned int r = v.u + 0x7FFFu + ((v.u >> 16) & 1u);
  return (unsigned short)(r >> 16);
}

DEVI void gload16(const unsigned short* g, unsigned short* lds_) {
  __builtin_amdgcn_global_load_lds(
      (const __attribute__((address_space(1))) unsigned int*)g,
      (__attribute__((address_space(3))) unsigned int*)lds_, 16, 0, 0);
}

DEVI f32x4 mfma16(bf16x8 a, bf16x8 b, f32x4 c) {
  return __builtin_amdgcn_mfma_f32_16x16x32_bf16(a, b, c, 0, 0, 0);
}

DEVI f32x16 mfma32(bf16x8 a, bf16x8 b, f32x16 c) {
  return __builtin_amdgcn_mfma_f32_32x32x16_bf16(a, b, c, 0, 0, 0);
}

DEVI float exp2g(float x) {
#if __has_builtin(__builtin_amdgcn_exp2f)
  return __builtin_amdgcn_exp2f(x);
#else
  return exp2f(x);
#endif
}

DEVI unsigned int cvtpk(float a, float b) {
  unsigned int r;
  asm("v_cvt_pk_bf16_f32 %0, %1, %2" : "=v"(r) : "v"(a), "v"(b));
  return r;
}

DEVI u32x2 pswap2(unsigned int a, unsigned int b) {
  return __builtin_amdgcn_permlane32_swap(a, b, false, false);
}
DEVI float xmax_halves(float v) {
  union { float f; unsigned int u; } c; c.f = v;
  u32x2 r = pswap2(c.u, c.u);
  union { unsigned int u; float f; } x, y; x.u = r.x; y.u = r.y;
  return fmaxf(x.f, y.f);
}

union U4 { unsigned int u[4]; bf16x8 v; };

// ---------------- prep: cast x -> bf16  +  transpose/cast W -> Wt ----------
__global__ __launch_bounds__(256) void prep_k(const float* __restrict__ x,
                                              const float* __restrict__ W,
                                              unsigned short* __restrict__ xb,
                                              unsigned short* __restrict__ Wt) {
  __shared__ float t[32][33];
  const int bid = blockIdx.x;
  if (bid < 4096) {
    int i = (bid * 256 + threadIdx.x) * 4;
    float4 v = *reinterpret_cast<const float4*>(x + i);
    ushort4 o;
    o.x = f2bf(v.x); o.y = f2bf(v.y); o.z = f2bf(v.z); o.w = f2bf(v.w);
    *reinterpret_cast<ushort4*>(xb + i) = o;
  } else {
    const int b2 = bid - 4096;
    const int c0 = (b2 % 96) * 32, k0 = (b2 / 96) * 32;
    const int tx = threadIdx.x & 31, ty = threadIdx.x >> 5;  // ty 0..7
#pragma unroll
    for (int r = 0; r < 32; r += 8)
      t[ty + r][tx] = W[(size_t)(k0 + ty + r) * D3 + c0 + tx];
    __syncthreads();
#pragma unroll
    for (int r = 0; r < 32; r += 8)
      Wt[(size_t)(c0 + ty + r) * D + k0 + tx] = f2bf(t[tx][ty + r]);
  }
}

// ---------------- QKV GEMM: [4096x1024] x [1024x3072] -------------
// 128x128 tile, BK=32, 2x2 waves of 64x64, 16x16x32 bf16 MFMA.
__global__ __launch_bounds__(256) void qkv_gemm_k(const unsigned short* __restrict__ xb,
                                                  const unsigned short* __restrict__ Wt,
                                                  unsigned short* __restrict__ qw,
                                                  unsigned short* __restrict__ kw,
                                                  unsigned short* __restrict__ vtw) {
  __shared__ unsigned short smA[128 * 32];
  __shared__ unsigned short smB[128 * 32];
  const int tid = threadIdx.x, w = tid >> 6, l = tid & 63;
  const int m0 = blockIdx.x * 128, n0 = blockIdx.y * 128;
  const int wm = w >> 1, wn = w & 1;

  const unsigned short* ga[2]; const unsigned short* gb[2];
  unsigned short* la[2]; unsigned short* lb[2];
#pragma unroll
  for (int i = 0; i < 2; ++i) {
    int idx = tid + i * 256;
    int row = idx >> 2;
    int blk = (idx & 3) ^ ((row >> 1) & 3);   // pre-swizzled global source
    ga[i] = xb + (size_t)(m0 + row) * D + blk * 8;
    gb[i] = Wt + (size_t)(n0 + row) * D + blk * 8;
    la[i] = smA + (w * 64 + i * 256) * 8;     // wave-uniform linear LDS dest
    lb[i] = smB + (w * 64 + i * 256) * 8;
  }

  f32x4 acc[4][4];
#pragma unroll
  for (int a = 0; a < 4; ++a)
#pragma unroll
    for (int b = 0; b < 4; ++b) acc[a][b] = (f32x4){0.f, 0.f, 0.f, 0.f};

  for (int kt = 0; kt < D / 32; ++kt) {
    __syncthreads();
#pragma unroll
    for (int i = 0; i < 2; ++i) {
      gload16(ga[i] + kt * 32, la[i]);
      gload16(gb[i] + kt * 32, lb[i]);
    }
    asm volatile("s_waitcnt vmcnt(0)" ::: "memory");
    __syncthreads();

    bf16x8 af[4], bfr[4];
#pragma unroll
    for (int a = 0; a < 4; ++a) {
      int arow = wm * 64 + a * 16 + (l & 15);
      int blk = (l >> 4) ^ ((arow >> 1) & 3);
      af[a] = *reinterpret_cast<const bf16x8*>(smA + arow * 32 + blk * 8);
    }
#pragma unroll
    for (int b = 0; b < 4; ++b) {
      int brow = wn * 64 + b * 16 + (l & 15);
      int blk = (l >> 4) ^ ((brow >> 1) & 3);
      bfr[b] = *reinterpret_cast<const bf16x8*>(smB + brow * 32 + blk * 8);
    }
#pragma unroll
    for (int a = 0; a < 4; ++a)
#pragma unroll
      for (int b = 0; b < 4; ++b)
        acc[a][b] = mfma16(af[a], bfr[b], acc[a][b]);
  }

  const int which = n0 >> 10;
#pragma unroll
  for (int a = 0; a < 4; ++a) {
#pragma unroll
    for (int b = 0; b < 4; ++b) {
#pragma unroll
      for (int r = 0; r < 4; ++r) {
        int grow = m0 + wm * 64 + a * 16 + (l >> 4) * 4 + r;
        int gcol = n0 + wn * 64 + b * 16 + (l & 15);
        float v = acc[a][b][r];
        int bb = grow >> 11, n = grow & 2047;
        int cc = gcol & 1023, h = cc >> 6, dh = cc & 63;
        size_t bh = (size_t)bb * NH + h;
        if (which == 0)
          qw[(bh * NSEQ + n) * 64 + dh] = f2bf(v * 0.18033688011112042f);
        else if (which == 1)
          kw[(bh * NSEQ + n) * 64 + dh] = f2bf(v);
        else
          vtw[(bh * 64 + dh) * NSEQ + n] = f2bf(v);
      }
    }
  }
}

// ---------------- causal flash attention: 32x32 MFMA, in-register P -------
// R10 structure; K-fragment loads hoisted ahead of the QK MFMA cluster
// (8 reads in flight -> one LDS latency) and V-fragment loads issued right
// after QK so their latency hides under softmax/pack (T14-lite).
__global__ __launch_bounds__(256, 2) void attn_k(const unsigned short* __restrict__ qw,
                                                 const unsigned short* __restrict__ kw,
                                                 const unsigned short* __restrict__ vtw,
                                                 float* __restrict__ out) {
  __shared__ __align__(16) char lds[66560];  // 2 slots x 32KB (KV pairs) + 1KB m/l
  const int tid = threadIdx.x, w = tid >> 6, l = tid & 63;
  const int hi = l >> 5, ql = l & 31;
  const int qsub = w >> 1, par = w & 1;

  const int wg = blockIdx.x;               // 512 blocks
  const int xcd = wg & 7, rest = wg >> 3;
  const int bhl = rest >> 4;               // local bh on this XCD
  const int j = rest & 15;                 // pair index
  const int bh = xcd * 4 + bhl;
  const int bb = bh >> 4, h = bh & 15;

  const unsigned short* qb = qw + (size_t)bh * NSEQ * 64;
  const unsigned short* kb = kw + (size_t)bh * NSEQ * 64;
  const unsigned short* vb = vtw + (size_t)bh * 64 * NSEQ;

  const int r0 = tid >> 3, c0 = (tid & 7) ^ (r0 & 7);
  const int r1 = (tid + 256) >> 3, c1 = ((tid + 256) & 7) ^ (r1 & 7);
  const int wbase = w * 512;               // ushorts: w*64 lanes * 8

#define STAGE(SL, PR)                                                            \
  do {                                                                           \
    const int t0_ = 2 * (PR), t1_ = 2 * (PR) + 1;                                \
    unsigned short* k0d = (unsigned short*)(lds + (SL) * 32768) + wbase;         \
    unsigned short* v0d = (unsigned short*)(lds + (SL) * 32768 + 8192) + wbase;  \
    unsigned short* k1d = (unsigned short*)(lds + (SL) * 32768 + 16384) + wbase; \
    unsigned short* v1d = (unsigned short*)(lds + (SL) * 32768 + 24576) + wbase; \
    gload16(kb + (((size_t)t0_ * 64 + r0) * 64 + c0 * 8), k0d);                  \
    gload16(kb + (((size_t)t0_ * 64 + r1) * 64 + c1 * 8), k0d + 2048);           \
    gload16(vb + ((size_t)r0 * NSEQ + t0_ * 64 + c0 * 8), v0d);                  \
    gload16(vb + ((size_t)r1 * NSEQ + t0_ * 64 + c1 * 8), v0d + 2048);           \
    gload16(kb + (((size_t)t1_ * 64 + r0) * 64 + c0 * 8), k1d);                  \
    gload16(kb + (((size_t)t1_ * 64 + r1) * 64 + c1 * 8), k1d + 2048);           \
    gload16(vb + ((size_t)r0 * NSEQ + t1_ * 64 + c0 * 8), v1d);                  \
    gload16(vb + ((size_t)r1 * NSEQ + t1_ * 64 + c1 * 8), v1d + 2048);           \
  } while (0)

  for (int seg = 0; seg < 2; ++seg) {
    const int qt = seg ? j : (31 - j);     // heavy q-tile first
    const int qbase = qt * 64;
    const int qg = qbase + qsub * 32 + ql; // this lane's q-row (global)

    bf16x8 qf[4];
#pragma unroll
    for (int ds = 0; ds < 4; ++ds)
      qf[ds] = *reinterpret_cast<const bf16x8*>(qb + (size_t)qg * 64 + ds * 16 + hi * 8);

    float m = -1e30f, lsum = 0.f;
    f32x16 O0, O1;
#pragma unroll
    for (int r2 = 0; r2 < 16; ++r2) { O0[r2] = 0.f; O1[r2] = 0.f; }

    const int nsup = (qt >> 1) + 1;
    STAGE(0, 0);
    for (int s = 0; s < nsup; ++s) {
      __syncthreads();                     // drains + publishes slot s&1
      if (s + 1 < nsup) STAGE((s + 1) & 1, s + 1);
      const int t = 2 * s + par;
      if (t <= qt) {
        const char* Kb = lds + (s & 1) * 32768 + par * 16384;
        const char* Vb = Kb + 8192;

        // hoisted K-fragment loads: 8 ds_read_b128 in flight before MFMAs
        bf16x8 kf[8];
#pragma unroll
        for (int ds = 0; ds < 4; ++ds) {
          kf[ds] = *reinterpret_cast<const bf16x8*>(
              Kb + ql * 128 + (((2 * ds + hi) ^ (ql & 7)) << 4));
          kf[4 + ds] = *reinterpret_cast<const bf16x8*>(
              Kb + (32 + ql) * 128 + (((2 * ds + hi) ^ (ql & 7)) << 4));
        }

        // QK: S^T[64k][32q], C rows=k, col q=ql
        f32x16 S0, S1;
#pragma unroll
        for (int r2 = 0; r2 < 16; ++r2) { S0[r2] = 0.f; S1[r2] = 0.f; }
        __builtin_amdgcn_s_setprio(1);
#pragma unroll
        for (int ds = 0; ds < 4; ++ds) {
          S0 = mfma32(kf[ds], qf[ds], S0);
          S1 = mfma32(kf[4 + ds], qf[ds], S1);
        }
        __builtin_amdgcn_s_setprio(0);

        // issue V-fragment loads NOW; latency hides under softmax/pack
        bf16x8 vf[8];
#pragma unroll
        for (int ks = 0; ks < 4; ++ks) {
          vf[ks] = *reinterpret_cast<const bf16x8*>(
              Vb + ql * 128 + (((2 * ks + hi) ^ (ql & 7)) << 4));
          vf[4 + ks] = *reinterpret_cast<const bf16x8*>(
              Vb + (32 + ql) * 128 + (((2 * ks + hi) ^ (ql & 7)) << 4));
        }

        if (t == qt) {  // causal mask on diagonal tile
#pragma unroll
          for (int reg = 0; reg < 16; ++reg) {
            const int krow = (reg & 3) + 8 * (reg >> 2) + 4 * hi;
            if (64 * t + krow > qg) S0[reg] = -1e30f;
            if (64 * t + 32 + krow > qg) S1[reg] = -1e30f;
          }
        }

        // row max: in-lane tree + one cross-half swap
        float t0 = fmaxf(S0[0], S1[0]), t1 = fmaxf(S0[1], S1[1]);
        float t2 = fmaxf(S0[2], S1[2]), t3 = fmaxf(S0[3], S1[3]);
#pragma unroll
        for (int r2 = 4; r2 < 16; r2 += 4) {
          t0 = fmaxf(t0, fmaxf(S0[r2], S1[r2]));
          t1 = fmaxf(t1, fmaxf(S0[r2 + 1], S1[r2 + 1]));
          t2 = fmaxf(t2, fmaxf(S0[r2 + 2], S1[r2 + 2]));
          t3 = fmaxf(t3, fmaxf(S0[r2 + 3], S1[r2 + 3]));
        }
        float tmax = xmax_halves(fmaxf(fmaxf(t0, t1), fmaxf(t2, t3)));

        if (!__all(tmax <= m + 8.0f)) {   // defer-max
          const float mn = fmaxf(m, tmax);
          const float g = exp2g(m - mn);
          m = mn;
          lsum *= g;
#pragma unroll
          for (int r2 = 0; r2 < 16; ++r2) { O0[r2] *= g; O1[r2] *= g; }
        }

        // exp + row sum
        float pr0[16], pr1[16];
        float rA = 0.f, rB = 0.f, rC = 0.f, rD = 0.f;
#pragma unroll
        for (int r2 = 0; r2 < 16; r2 += 4) {
          pr0[r2] = exp2g(S0[r2] - m);     pr1[r2] = exp2g(S1[r2] - m);
          pr0[r2 + 1] = exp2g(S0[r2 + 1] - m); pr1[r2 + 1] = exp2g(S1[r2 + 1] - m);
          pr0[r2 + 2] = exp2g(S0[r2 + 2] - m); pr1[r2 + 2] = exp2g(S1[r2 + 2] - m);
          pr0[r2 + 3] = exp2g(S0[r2 + 3] - m); pr1[r2 + 3] = exp2g(S1[r2 + 3] - m);
          rA += pr0[r2] + pr1[r2];
          rB += pr0[r2 + 1] + pr1[r2 + 1];
          rC += pr0[r2 + 2] + pr1[r2 + 2];
          rD += pr0[r2 + 3] + pr1[r2 + 3];
        }
        {
          float rsum = (rA + rB) + (rC + rD);
          union { float f; unsigned int u; } c; c.f = rsum;
          u32x2 r = pswap2(c.u, c.u);
          union { unsigned int u; float f; } x, y; x.u = r.x; y.u = r.y;
          lsum += x.f + y.f;
        }

        // pack P into PV B-frags: cvt_pk + permlane32_swap
        bf16x8 pf[4];
#pragma unroll
        for (int ct = 0; ct < 2; ++ct) {
          const float* pp = ct ? pr1 : pr0;
          unsigned int u[4][2];
#pragma unroll
          for (int c = 0; c < 4; ++c) {
            u[c][0] = cvtpk(pp[4 * c], pp[4 * c + 1]);
            u[c][1] = cvtpk(pp[4 * c + 2], pp[4 * c + 3]);
          }
#pragma unroll
          for (int kk = 0; kk < 2; ++kk) {
            u32x2 rw0 = pswap2(u[2 * kk][0], u[2 * kk + 1][0]);
            u32x2 rw1 = pswap2(u[2 * kk][1], u[2 * kk + 1][1]);
            U4 f;
            f.u[0] = rw0.x; f.u[1] = rw1.x;
            f.u[2] = rw0.y; f.u[3] = rw1.y;
            pf[2 * ct + kk] = f.v;
          }
        }

        // PV: O^T[64d][32q] += V^T-frag x P-frag (vf already resident)
        __builtin_amdgcn_s_setprio(1);
#pragma unroll
        for (int ks = 0; ks < 4; ++ks) {
          O0 = mfma32(vf[ks], pf[ks], O0);
          O1 = mfma32(vf[4 + ks], pf[ks], O1);
        }
        __builtin_amdgcn_s_setprio(0);
      }
    }

    // ---- merge k-split parities (log-sum-exp) + epilogue ----
    __syncthreads();
    float* mlp = (float*)(lds + 65536);
    if (l < 32) { mlp[w * 64 + l] = m; mlp[w * 64 + 32 + l] = lsum; }
    __syncthreads();
    {
      const int pw = w ^ 1;
      const float m1 = mlp[pw * 64 + ql];
      const float l1 = mlp[pw * 64 + 32 + ql];
      const float M = fmaxf(m, m1);
      const float g0 = exp2g(m - M);
      const float g1 = exp2g(m1 - M);
      const float L = lsum * g0 + l1 * g1;
      const float phi = g0 / L;
      float* mo = (float*)lds + (qsub * 2 + par) * 2048;  // [32q][64d] swizzled
#pragma unroll
      for (int reg = 0; reg < 16; ++reg) {
        const int dr = (reg & 3) + 8 * (reg >> 2) + 4 * hi;
        const int d1 = 32 + dr;
        mo[ql * 64 + (((dr >> 2) ^ (ql & 7)) << 2) + (dr & 3)] = O0[reg] * phi;
        mo[ql * 64 + (((d1 >> 2) ^ (ql & 7)) << 2) + (d1 & 3)] = O1[reg] * phi;
      }
    }
    __syncthreads();
    {
      const int qq = tid >> 2, dq = (tid & 3) << 4;
      const float* pa = (float*)lds + ((qq >> 5) * 2 + 0) * 2048 + (qq & 31) * 64;
      const float* pb = (float*)lds + ((qq >> 5) * 2 + 1) * 2048 + (qq & 31) * 64;
      float* op = out + ((size_t)bb * NSEQ + qbase + qq) * D + h * 64 + dq;
#pragma unroll
      for (int c = 0; c < 4; ++c) {
        const int ch = ((dq >> 2) + c) ^ (qq & 7);
        float4 va = *reinterpret_cast<const float4*>(pa + ch * 4);
        float4 vb4 = *reinterpret_cast<const float4*>(pb + ch * 4);
        float4 s4 = make_float4(va.x + vb4.x, va.y + vb4.y, va.z + vb4.z, va.w + vb4.w);
        *reinterpret_cast<float4*>(op + c * 4) = s4;
      }
    }
    __syncthreads();   // protect LDS before next segment's prologue STAGE
  }
#undef STAGE
}

extern "C" void kernel_launch(void* const* d_in, const int* in_sizes, int n_in,
                              void* d_out, int out_size, void* d_ws, size_t ws_size,
                              hipStream_t stream) {
  const float* x = (const float*)d_in[0];
  const float* W = (const float*)d_in[1];
  float* out = (float*)d_out;
  char* ws = (char*)d_ws;
  unsigned short* xb  = (unsigned short*)(ws);               // 8 MB
  unsigned short* Wt  = (unsigned short*)(ws + 8388608);     // 6 MB
  unsigned short* qw  = (unsigned short*)(ws + 14680064);    // 8 MB
  unsigned short* kw  = (unsigned short*)(ws + 23068672);    // 8 MB
  unsigned short* vtw = (unsigned short*)(ws + 31457280);    // 8 MB

  prep_k<<<7168, 256, 0, stream>>>(x, W, xb, Wt);
  qkv_gemm_k<<<dim3(32, 24), 256, 0, stream>>>(xb, Wt, qw, kw, vtw);
  attn_k<<<512, 256, 0, stream>>>(qw, kw, vtw, out);
}